// Round 8
// baseline (314.117 us; speedup 1.0000x reference)
//
#include <hip/hip_runtime.h>
#include <hip/hip_bf16.h>

#define ALPHA 0.2f
#define IN_DIM 256
#define HD 256      // HEADS*OUT_DIM
#define HEADS 4

typedef short short8 __attribute__((ext_vector_type(8)));
typedef float f32x4 __attribute__((ext_vector_type(4)));

__device__ __forceinline__ float lrelu(float x) { return x > 0.f ? x : ALPHA * x; }

__device__ __forceinline__ unsigned short f2bf(float x) {  // RTNE f32->bf16
  unsigned int u = __builtin_bit_cast(unsigned int, x);
  unsigned int r = (u + 0x7fffu + ((u >> 16) & 1u)) >> 16;
  return (unsigned short)r;
}
__device__ __forceinline__ float bf2f(unsigned short h) {
  unsigned int u = ((unsigned int)h) << 16;
  return __builtin_bit_cast(float, u);
}
// packed bf16 pair -> f32 (low / high element)
__device__ __forceinline__ float bflo(unsigned int u) {
  return __builtin_bit_cast(float, u << 16);
}
__device__ __forceinline__ float bfhi(unsigned int u) {
  return __builtin_bit_cast(float, u & 0xffff0000u);
}
// order-preserving float<->uint encoding for atomicMax
__device__ __forceinline__ unsigned int fenc(float x) {
  unsigned int u = __builtin_bit_cast(unsigned int, x);
  return (u & 0x80000000u) ? ~u : (u | 0x80000000u);
}
__device__ __forceinline__ float fdec(unsigned int k) {
  unsigned int u = (k & 0x80000000u) ? (k ^ 0x80000000u) : ~k;
  return __builtin_bit_cast(float, u);
}
#define MKEY_INIT 0x007fffffu   // fenc(-inf)

// ---------------------------------------------------------------------------
// K0: W (f32 [256][256]) -> hi/lo bf16, PERMUTED into MFMA-fragment order:
//   uint4 dst idx = (((head*8+ks)*4+nt)*4+g)*16 + m15
// so a wave's B-fragment load (lane = g*16+m15) is one contiguous 1KB line.
// ---------------------------------------------------------------------------
__global__ __launch_bounds__(256) void wcvt_kernel(
    const float* __restrict__ W, uint4* __restrict__ whi,
    uint4* __restrict__ wlo) {
  int u = blockIdx.x * 256 + threadIdx.x;   // source uint4 index
  int n = u >> 5, c = u & 31;               // row, k-chunk
  int ks = c >> 2, g = c & 3;
  int head = n >> 6, nt = (n >> 4) & 3, m15 = n & 15;
  const float* gp = &W[(size_t)u * 8];
  float4 f0 = *(const float4*)gp;
  float4 f1 = *(const float4*)(gp + 4);
  float ff[8] = {f0.x, f0.y, f0.z, f0.w, f1.x, f1.y, f1.z, f1.w};
  unsigned int hh[8], ll[8];
#pragma unroll
  for (int k = 0; k < 8; ++k) {
    unsigned short h = f2bf(ff[k]);
    hh[k] = h;
    ll[k] = f2bf(ff[k] - bf2f(h));
  }
  uint4 ph, pl;
  ph.x = hh[0] | (hh[1] << 16); ph.y = hh[2] | (hh[3] << 16);
  ph.z = hh[4] | (hh[5] << 16); ph.w = hh[6] | (hh[7] << 16);
  pl.x = ll[0] | (ll[1] << 16); pl.y = ll[2] | (ll[3] << 16);
  pl.z = ll[4] | (ll[5] << 16); pl.w = ll[6] | (ll[7] << 16);
  int dst = (((head * 8 + ks) * 4 + nt) * 4 + g) * 16 + m15;
  whi[dst] = ph;
  wlo[dst] = pl;
}

// ---------------------------------------------------------------------------
// K0b: degree histogram
// ---------------------------------------------------------------------------
__global__ __launch_bounds__(256) void deg_kernel(
    const int* __restrict__ dst, int* __restrict__ deg, int E) {
  int i = blockIdx.x * blockDim.x + threadIdx.x;
  if (i < E) atomicAdd(&deg[dst[i]], 1);
}

// ---------------------------------------------------------------------------
// K1: split-precision MFMA projection (triple MFMA: hi*hi + hi*lo + lo*hi).
// M-tile 32 rows (LDS 32KB), N = 256 (wave w owns head w).
// ---------------------------------------------------------------------------
__global__ __launch_bounds__(256, 4) void gemm_mfma(
    const float* __restrict__ feat, const uint4* __restrict__ whi,
    const uint4* __restrict__ wlo,
    const float* __restrict__ attn_l, const float* __restrict__ attn_r,
    unsigned short* __restrict__ ftb, float* __restrict__ a1,
    float* __restrict__ a2, int N) {
  __shared__ uint4 ldsh[1024];  // A-hi: 32 rows x 512B, swizzled
  __shared__ uint4 ldsl[1024];  // A-lo
  const int tid = threadIdx.x;
  const int row0 = blockIdx.x * 32;

#pragma unroll
  for (int it = 0; it < 4; ++it) {
    int ci = tid + it * 256;
    int row = ci >> 5, c16 = ci & 31;
    int grow = row0 + row;
    uint4 ph = uint4{0u, 0u, 0u, 0u}, pl = uint4{0u, 0u, 0u, 0u};
    if (grow < N) {
      const float* gp = &feat[(size_t)grow * IN_DIM + c16 * 8];
      float4 f0 = *(const float4*)gp;
      float4 f1 = *(const float4*)(gp + 4);
      float ff[8] = {f0.x, f0.y, f0.z, f0.w, f1.x, f1.y, f1.z, f1.w};
      unsigned int hh[8], ll[8];
#pragma unroll
      for (int k = 0; k < 8; ++k) {
        unsigned short h = f2bf(ff[k]);
        hh[k] = h;
        ll[k] = f2bf(ff[k] - bf2f(h));
      }
      ph.x = hh[0] | (hh[1] << 16); ph.y = hh[2] | (hh[3] << 16);
      ph.z = hh[4] | (hh[5] << 16); ph.w = hh[6] | (hh[7] << 16);
      pl.x = ll[0] | (ll[1] << 16); pl.y = ll[2] | (ll[3] << 16);
      pl.z = ll[4] | (ll[5] << 16); pl.w = ll[6] | (ll[7] << 16);
    }
    int idx = (row * 512 + ((c16 * 16) ^ ((row & 7) << 4))) >> 4;
    ldsh[idx] = ph;
    ldsl[idx] = pl;
  }
  __syncthreads();

  const int lane = tid & 63;
  const int w = tid >> 6;   // wave id == head id == N-quadrant
  const int m15 = lane & 15;
  const int g = lane >> 4;  // k-group 0..3

  f32x4 acc[2][4];
#pragma unroll
  for (int mt = 0; mt < 2; ++mt)
#pragma unroll
    for (int nt = 0; nt < 4; ++nt) acc[mt][nt] = f32x4{0.f, 0.f, 0.f, 0.f};

  for (int ks = 0; ks < 8; ++ks) {       // K = 8 * 32
    short8 ah[2], al_[2], bh[4], bl[4];
#pragma unroll
    for (int mt = 0; mt < 2; ++mt) {
      int row = mt * 16 + m15;
      int idx = (row * 512 + ((ks * 64 + g * 16) ^ ((row & 7) << 4))) >> 4;
      ah[mt] = __builtin_bit_cast(short8, ldsh[idx]);
      al_[mt] = __builtin_bit_cast(short8, ldsl[idx]);
    }
#pragma unroll
    for (int nt = 0; nt < 4; ++nt) {
      int idx = (((w * 8 + ks) * 4 + nt) * 4 + g) * 16 + m15;
      bh[nt] = __builtin_bit_cast(short8, whi[idx]);
      bl[nt] = __builtin_bit_cast(short8, wlo[idx]);
    }
#pragma unroll
    for (int mt = 0; mt < 2; ++mt)
#pragma unroll
      for (int nt = 0; nt < 4; ++nt) {
        acc[mt][nt] = __builtin_amdgcn_mfma_f32_16x16x32_bf16(
            ah[mt], bh[nt], acc[mt][nt], 0, 0, 0);
        acc[mt][nt] = __builtin_amdgcn_mfma_f32_16x16x32_bf16(
            ah[mt], bl[nt], acc[mt][nt], 0, 0, 0);
        acc[mt][nt] = __builtin_amdgcn_mfma_f32_16x16x32_bf16(
            al_[mt], bh[nt], acc[mt][nt], 0, 0, 0);
      }
  }

  // epilogue: ft (bf16) + fused a1/a2 (f32)
  float al[4], ar[4];
#pragma unroll
  for (int nt = 0; nt < 4; ++nt) {
    al[nt] = attn_l[w * 64 + nt * 16 + m15];
    ar[nt] = attn_r[w * 64 + nt * 16 + m15];
  }
#pragma unroll
  for (int mt = 0; mt < 2; ++mt) {
#pragma unroll
    for (int r = 0; r < 4; ++r) {
      int rloc = mt * 16 + g * 4 + r;  // C/D: row=(lane>>4)*4+reg (m89)
      int row = row0 + rloc;
      float v1 = 0.f, v2 = 0.f;
#pragma unroll
      for (int nt = 0; nt < 4; ++nt) {
        float v = acc[mt][nt][r];
        v1 += v * al[nt];
        v2 += v * ar[nt];
        if (row < N)
          ftb[(size_t)row * HD + w * 64 + nt * 16 + m15] = f2bf(v);
      }
#pragma unroll
      for (int o = 8; o; o >>= 1) {
        v1 += __shfl_xor(v1, o);
        v2 += __shfl_xor(v2, o);
      }
      if (m15 == 0 && row < N) {
        a1[(size_t)row * HEADS + w] = v1;
        a2[(size_t)row * HEADS + w] = v2;
      }
    }
  }
}

// ---------------------------------------------------------------------------
// K3a: per-block partial sums of deg + init of mkey (segment-max keys)
// ---------------------------------------------------------------------------
__global__ __launch_bounds__(256) void scan_part(
    const int* __restrict__ deg, int* __restrict__ bsum,
    unsigned int* __restrict__ mkey, int n) {
  const int tid = threadIdx.x;
  int base = (blockIdx.x * 256 + tid) * 4;
  int s = 0;
  if (base + 3 < n) {
    int4 v = *(const int4*)&deg[base];
    s = v.x + v.y + v.z + v.w;
    uint4 iv = uint4{MKEY_INIT, MKEY_INIT, MKEY_INIT, MKEY_INIT};
    uint4* mp = (uint4*)&mkey[(size_t)base * HEADS];
    mp[0] = iv; mp[1] = iv; mp[2] = iv; mp[3] = iv;
  } else {
#pragma unroll
    for (int k = 0; k < 4; ++k)
      if (base + k < n) {
        s += deg[base + k];
#pragma unroll
        for (int h = 0; h < HEADS; ++h)
          mkey[(size_t)(base + k) * HEADS + h] = MKEY_INIT;
      }
  }
#pragma unroll
  for (int o = 32; o; o >>= 1) s += __shfl_xor(s, o);
  __shared__ int ws[4];
  if ((tid & 63) == 0) ws[tid >> 6] = s;
  __syncthreads();
  if (tid == 0) bsum[blockIdx.x] = ws[0] + ws[1] + ws[2] + ws[3];
}

// ---------------------------------------------------------------------------
// K3b: single-wave scan of block sums -> exclusive block offsets + rowptr[n]
// ---------------------------------------------------------------------------
__global__ __launch_bounds__(64) void scan_block(
    const int* __restrict__ bsum, int* __restrict__ boff,
    int* __restrict__ rowptr, int nb, int n) {
  int lane = threadIdx.x;
  int v = (lane < nb) ? bsum[lane] : 0;
  int orig = v;
#pragma unroll
  for (int o = 1; o < 64; o <<= 1) {
    int t = __shfl_up(v, o);
    if (lane >= o) v += t;
  }
  if (lane < nb) boff[lane] = v - orig;
  if (lane == nb - 1) rowptr[n] = v;
}

// ---------------------------------------------------------------------------
// K3c: emit rowptr (block-wide scan over 256 thread sums + int4 stores)
// ---------------------------------------------------------------------------
__global__ __launch_bounds__(256) void scan_emit(
    const int* __restrict__ deg, const int* __restrict__ boff,
    int* __restrict__ rowptr, int n) {
  __shared__ int buf[256];
  const int tid = threadIdx.x;
  int base = (blockIdx.x * 256 + tid) * 4;
  int d0 = 0, d1 = 0, d2 = 0, d3 = 0;
  if (base + 3 < n) {
    int4 v = *(const int4*)&deg[base];
    d0 = v.x; d1 = v.y; d2 = v.z; d3 = v.w;
  } else {
    if (base < n) d0 = deg[base];
    if (base + 1 < n) d1 = deg[base + 1];
    if (base + 2 < n) d2 = deg[base + 2];
    if (base + 3 < n) d3 = deg[base + 3];
  }
  int s = d0 + d1 + d2 + d3;
  buf[tid] = s;
  __syncthreads();
  for (int d = 1; d < 256; d <<= 1) {
    int v = (tid >= d) ? buf[tid - d] : 0;
    __syncthreads();
    buf[tid] += v;
    __syncthreads();
  }
  int excl = buf[tid] - s + boff[blockIdx.x];
  if (base + 3 < n) {
    int4 o;
    o.x = excl;
    o.y = excl + d0;
    o.z = excl + d0 + d1;
    o.w = excl + d0 + d1 + d2;
    *(int4*)&rowptr[base] = o;
  } else {
    int off = excl;
    if (base < n)     { rowptr[base] = off;     off += d0; }
    if (base + 1 < n) { rowptr[base + 1] = off; off += d1; }
    if (base + 2 < n) { rowptr[base + 2] = off; off += d2; }
    if (base + 3 < n) { rowptr[base + 3] = off; }
  }
}

// ---------------------------------------------------------------------------
// K4: fused edge-score + CSR scatter + segment-max (atomicMax on encoded e).
// ---------------------------------------------------------------------------
__global__ __launch_bounds__(256) void edge_scatter_kernel(
    const float* __restrict__ a1, const float* __restrict__ a2,
    const int* __restrict__ src, const int* __restrict__ dst,
    const int* __restrict__ rowptr, int* __restrict__ cursor,
    float* __restrict__ csr_e, int* __restrict__ csr_src,
    unsigned int* __restrict__ mkey, int E) {
  int i = blockIdx.x * blockDim.x + threadIdx.x;
  if (i >= E) return;
  int s_ = src[i], d_ = dst[i];
  float4 va = ((const float4*)a1)[s_];
  float4 vb = ((const float4*)a2)[d_];
  float4 r;
  r.x = lrelu(va.x + vb.x);
  r.y = lrelu(va.y + vb.y);
  r.z = lrelu(va.z + vb.z);
  r.w = lrelu(va.w + vb.w);
  int pos = rowptr[d_] + atomicAdd(&cursor[d_], 1);
  ((float4*)csr_e)[pos] = r;
  csr_src[pos] = s_;
  unsigned int* mp = &mkey[(size_t)d_ * HEADS];
  atomicMax(&mp[0], fenc(r.x));
  atomicMax(&mp[1], fenc(r.y));
  atomicMax(&mp[2], fenc(r.z));
  atomicMax(&mp[3], fenc(r.w));
}

// ---------------------------------------------------------------------------
// K5: single-pass softmax-weighted aggregation + ELU. One wave per node.
// Max precomputed (mkey); every lane computes ex locally (sum needs no
// reduce since every lane sees every edge). No LDS. x8 unroll = 8 gathers
// in flight per wave.
// ---------------------------------------------------------------------------
__global__ __launch_bounds__(256) void aggregate_kernel(
    const unsigned short* __restrict__ ftb, const float* __restrict__ csr_e,
    const int* __restrict__ csr_src, const int* __restrict__ rowptr,
    const unsigned int* __restrict__ mkey, float* __restrict__ out, int N) {
  const int tid = threadIdx.x;
  const int wv = tid >> 6;
  const int lane = tid & 63;
  const int n = blockIdx.x * 4 + wv;
  if (n >= N) return;
  const int hg = lane >> 4;   // head of this lane
  const int start = rowptr[n];
  const int cnt = rowptr[n + 1] - start;

  const float mx = fdec(mkey[(size_t)n * HEADS + hg]);
  const size_t col = (size_t)(lane * 4);

  float sm = 0.f;
  float a0 = 0.f, b0 = 0.f, c0 = 0.f, d0 = 0.f;
  int j = 0;
  for (; j + 8 <= cnt; j += 8) {
    int s[8];
    uint2 u[8];
    float ex[8];
#pragma unroll
    for (int k = 0; k < 8; ++k) s[k] = csr_src[start + j + k];
#pragma unroll
    for (int k = 0; k < 8; ++k)
      u[k] = *(const uint2*)&ftb[(size_t)s[k] * HD + col];
#pragma unroll
    for (int k = 0; k < 8; ++k)
      ex[k] = __expf(csr_e[(size_t)(start + j + k) * HEADS + hg] - mx);
#pragma unroll
    for (int k = 0; k < 8; ++k) {
      sm += ex[k];
      a0 += ex[k] * bflo(u[k].x); b0 += ex[k] * bfhi(u[k].x);
      c0 += ex[k] * bflo(u[k].y); d0 += ex[k] * bfhi(u[k].y);
    }
  }
  for (; j < cnt; ++j) {
    float ex = __expf(csr_e[(size_t)(start + j) * HEADS + hg] - mx);
    uint2 u = *(const uint2*)&ftb[(size_t)csr_src[start + j] * HD + col];
    sm += ex;
    a0 += ex * bflo(u.x); b0 += ex * bfhi(u.x);
    c0 += ex * bflo(u.y); d0 += ex * bfhi(u.y);
  }
  float inv = (cnt > 0) ? 1.f / sm : 0.f;
  a0 *= inv; b0 *= inv; c0 *= inv; d0 *= inv;
  float4 o4;
  o4.x = a0 > 0.f ? a0 : (__expf(a0) - 1.f);
  o4.y = b0 > 0.f ? b0 : (__expf(b0) - 1.f);
  o4.z = c0 > 0.f ? c0 : (__expf(c0) - 1.f);
  o4.w = d0 > 0.f ? d0 : (__expf(d0) - 1.f);
  *(float4*)&out[(size_t)n * HD + col] = o4;
}

// ---------------------------------------------------------------------------
extern "C" void kernel_launch(void* const* d_in, const int* in_sizes, int n_in,
                              void* d_out, int out_size, void* d_ws, size_t ws_size,
                              hipStream_t stream) {
  const float* feat   = (const float*)d_in[0];
  const int*   src    = (const int*)d_in[1];
  const int*   dst    = (const int*)d_in[2];
  const float* W      = (const float*)d_in[3];
  const float* attn_l = (const float*)d_in[4];
  const float* attn_r = (const float*)d_in[5];
  float* out = (float*)d_out;

  const int N = in_sizes[0] / IN_DIM;   // 50000
  const int E = in_sizes[1];            // 800000

  size_t off = 0;
  auto alloc = [&](size_t bytes) -> void* {
    void* p = (char*)d_ws + off;
    off = (off + bytes + 255) & ~(size_t)255;
    return p;
  };
  unsigned short* ftb = (unsigned short*)alloc((size_t)N * HD * 2);
  uint4* whi     = (uint4*)alloc((size_t)HD * IN_DIM * 2);
  uint4* wlo     = (uint4*)alloc((size_t)HD * IN_DIM * 2);
  float* a1      = (float*)alloc((size_t)N * HEADS * 4);
  float* a2      = (float*)alloc((size_t)N * HEADS * 4);
  float* csr_e   = (float*)alloc((size_t)E * HEADS * 4);
  int*   csr_src = (int*)alloc((size_t)E * 4);
  int*   deg     = (int*)alloc((size_t)2 * N * 4);   // deg + cursor
  int*   cursor  = deg + N;
  int*   rowptr  = (int*)alloc((size_t)(N + 1) * 4);
  unsigned int* mkey = (unsigned int*)alloc((size_t)N * HEADS * 4);
  int*   bsum    = (int*)alloc(64 * 4);
  int*   boff    = (int*)alloc(64 * 4);
  (void)ws_size;

  hipMemsetAsync(deg, 0, (size_t)2 * N * 4, stream);

  const int eb = (E + 255) / 256;
  const int nb = (N + 1023) / 1024;   // scan blocks (<= 64)
  wcvt_kernel<<<32, 256, 0, stream>>>(W, whi, wlo);
  deg_kernel<<<eb, 256, 0, stream>>>(dst, deg, E);
  scan_part<<<nb, 256, 0, stream>>>(deg, bsum, mkey, N);
  scan_block<<<1, 64, 0, stream>>>(bsum, boff, rowptr, nb, N);
  scan_emit<<<nb, 256, 0, stream>>>(deg, boff, rowptr, N);
  gemm_mfma<<<(N + 31) / 32, 256, 0, stream>>>(feat, whi, wlo, attn_l, attn_r,
                                               ftb, a1, a2, N);
  edge_scatter_kernel<<<eb, 256, 0, stream>>>(a1, a2, src, dst, rowptr, cursor,
                                              csr_e, csr_src, mkey, E);
  aggregate_kernel<<<(N + 3) / 4, 256, 0, stream>>>(ftb, csr_e, csr_src,
                                                    rowptr, mkey, out, N);
}

// Round 9
// 197.623 us; speedup vs baseline: 1.5895x; 1.5895x over previous
//
#include <hip/hip_runtime.h>
#include <hip/hip_bf16.h>

#define ALPHA 0.2f
#define IN_DIM 256
#define HD 256      // HEADS*OUT_DIM
#define HEADS 4

typedef short short8 __attribute__((ext_vector_type(8)));
typedef float f32x4 __attribute__((ext_vector_type(4)));

__device__ __forceinline__ float lrelu(float x) { return x > 0.f ? x : ALPHA * x; }

__device__ __forceinline__ unsigned short f2bf(float x) {  // RTNE f32->bf16
  unsigned int u = __builtin_bit_cast(unsigned int, x);
  unsigned int r = (u + 0x7fffu + ((u >> 16) & 1u)) >> 16;
  return (unsigned short)r;
}
__device__ __forceinline__ float bf2f(unsigned short h) {
  unsigned int u = ((unsigned int)h) << 16;
  return __builtin_bit_cast(float, u);
}
// packed bf16 pair -> f32 (low / high element)
__device__ __forceinline__ float bflo(unsigned int u) {
  return __builtin_bit_cast(float, u << 16);
}
__device__ __forceinline__ float bfhi(unsigned int u) {
  return __builtin_bit_cast(float, u & 0xffff0000u);
}

// ---------------------------------------------------------------------------
// K0: W (f32 [256][256]) -> hi/lo bf16, PERMUTED into MFMA-fragment order:
//   uint4 dst idx = (((head*8+ks)*4+nt)*4+g)*16 + m15
// ---------------------------------------------------------------------------
__global__ __launch_bounds__(256) void wcvt_kernel(
    const float* __restrict__ W, uint4* __restrict__ whi,
    uint4* __restrict__ wlo) {
  int u = blockIdx.x * 256 + threadIdx.x;   // source uint4 index
  int n = u >> 5, c = u & 31;               // row, k-chunk
  int ks = c >> 2, g = c & 3;
  int head = n >> 6, nt = (n >> 4) & 3, m15 = n & 15;
  const float* gp = &W[(size_t)u * 8];
  float4 f0 = *(const float4*)gp;
  float4 f1 = *(const float4*)(gp + 4);
  float ff[8] = {f0.x, f0.y, f0.z, f0.w, f1.x, f1.y, f1.z, f1.w};
  unsigned int hh[8], ll[8];
#pragma unroll
  for (int k = 0; k < 8; ++k) {
    unsigned short h = f2bf(ff[k]);
    hh[k] = h;
    ll[k] = f2bf(ff[k] - bf2f(h));
  }
  uint4 ph, pl;
  ph.x = hh[0] | (hh[1] << 16); ph.y = hh[2] | (hh[3] << 16);
  ph.z = hh[4] | (hh[5] << 16); ph.w = hh[6] | (hh[7] << 16);
  pl.x = ll[0] | (ll[1] << 16); pl.y = ll[2] | (ll[3] << 16);
  pl.z = ll[4] | (ll[5] << 16); pl.w = ll[6] | (ll[7] << 16);
  int dst = (((head * 8 + ks) * 4 + nt) * 4 + g) * 16 + m15;
  whi[dst] = ph;
  wlo[dst] = pl;
}

// ---------------------------------------------------------------------------
// K0b: degree histogram
// ---------------------------------------------------------------------------
__global__ __launch_bounds__(256) void deg_kernel(
    const int* __restrict__ dst, int* __restrict__ deg, int E) {
  int i = blockIdx.x * blockDim.x + threadIdx.x;
  if (i < E) atomicAdd(&deg[dst[i]], 1);
}

// ---------------------------------------------------------------------------
// K1: split-precision MFMA projection (triple MFMA: hi*hi + hi*lo + lo*hi).
// M-tile 32 rows (LDS 32KB), N = 256 (wave w owns head w).
// ---------------------------------------------------------------------------
__global__ __launch_bounds__(256, 4) void gemm_mfma(
    const float* __restrict__ feat, const uint4* __restrict__ whi,
    const uint4* __restrict__ wlo,
    const float* __restrict__ attn_l, const float* __restrict__ attn_r,
    unsigned short* __restrict__ ftb, float* __restrict__ a1,
    float* __restrict__ a2, int N) {
  __shared__ uint4 ldsh[1024];  // A-hi: 32 rows x 512B, swizzled
  __shared__ uint4 ldsl[1024];  // A-lo
  const int tid = threadIdx.x;
  const int row0 = blockIdx.x * 32;

#pragma unroll
  for (int it = 0; it < 4; ++it) {
    int ci = tid + it * 256;
    int row = ci >> 5, c16 = ci & 31;
    int grow = row0 + row;
    uint4 ph = uint4{0u, 0u, 0u, 0u}, pl = uint4{0u, 0u, 0u, 0u};
    if (grow < N) {
      const float* gp = &feat[(size_t)grow * IN_DIM + c16 * 8];
      float4 f0 = *(const float4*)gp;
      float4 f1 = *(const float4*)(gp + 4);
      float ff[8] = {f0.x, f0.y, f0.z, f0.w, f1.x, f1.y, f1.z, f1.w};
      unsigned int hh[8], ll[8];
#pragma unroll
      for (int k = 0; k < 8; ++k) {
        unsigned short h = f2bf(ff[k]);
        hh[k] = h;
        ll[k] = f2bf(ff[k] - bf2f(h));
      }
      ph.x = hh[0] | (hh[1] << 16); ph.y = hh[2] | (hh[3] << 16);
      ph.z = hh[4] | (hh[5] << 16); ph.w = hh[6] | (hh[7] << 16);
      pl.x = ll[0] | (ll[1] << 16); pl.y = ll[2] | (ll[3] << 16);
      pl.z = ll[4] | (ll[5] << 16); pl.w = ll[6] | (ll[7] << 16);
    }
    int idx = (row * 512 + ((c16 * 16) ^ ((row & 7) << 4))) >> 4;
    ldsh[idx] = ph;
    ldsl[idx] = pl;
  }
  __syncthreads();

  const int lane = tid & 63;
  const int w = tid >> 6;   // wave id == head id == N-quadrant
  const int m15 = lane & 15;
  const int g = lane >> 4;  // k-group 0..3

  f32x4 acc[2][4];
#pragma unroll
  for (int mt = 0; mt < 2; ++mt)
#pragma unroll
    for (int nt = 0; nt < 4; ++nt) acc[mt][nt] = f32x4{0.f, 0.f, 0.f, 0.f};

  for (int ks = 0; ks < 8; ++ks) {       // K = 8 * 32
    short8 ah[2], al_[2], bh[4], bl[4];
#pragma unroll
    for (int mt = 0; mt < 2; ++mt) {
      int row = mt * 16 + m15;
      int idx = (row * 512 + ((ks * 64 + g * 16) ^ ((row & 7) << 4))) >> 4;
      ah[mt] = __builtin_bit_cast(short8, ldsh[idx]);
      al_[mt] = __builtin_bit_cast(short8, ldsl[idx]);
    }
#pragma unroll
    for (int nt = 0; nt < 4; ++nt) {
      int idx = (((w * 8 + ks) * 4 + nt) * 4 + g) * 16 + m15;
      bh[nt] = __builtin_bit_cast(short8, whi[idx]);
      bl[nt] = __builtin_bit_cast(short8, wlo[idx]);
    }
#pragma unroll
    for (int mt = 0; mt < 2; ++mt)
#pragma unroll
      for (int nt = 0; nt < 4; ++nt) {
        acc[mt][nt] = __builtin_amdgcn_mfma_f32_16x16x32_bf16(
            ah[mt], bh[nt], acc[mt][nt], 0, 0, 0);
        acc[mt][nt] = __builtin_amdgcn_mfma_f32_16x16x32_bf16(
            ah[mt], bl[nt], acc[mt][nt], 0, 0, 0);
        acc[mt][nt] = __builtin_amdgcn_mfma_f32_16x16x32_bf16(
            al_[mt], bh[nt], acc[mt][nt], 0, 0, 0);
      }
  }

  // epilogue: ft (bf16) + fused a1/a2 (f32)
  float al[4], ar[4];
#pragma unroll
  for (int nt = 0; nt < 4; ++nt) {
    al[nt] = attn_l[w * 64 + nt * 16 + m15];
    ar[nt] = attn_r[w * 64 + nt * 16 + m15];
  }
#pragma unroll
  for (int mt = 0; mt < 2; ++mt) {
#pragma unroll
    for (int r = 0; r < 4; ++r) {
      int rloc = mt * 16 + g * 4 + r;  // C/D: row=(lane>>4)*4+reg (m89)
      int row = row0 + rloc;
      float v1 = 0.f, v2 = 0.f;
#pragma unroll
      for (int nt = 0; nt < 4; ++nt) {
        float v = acc[mt][nt][r];
        v1 += v * al[nt];
        v2 += v * ar[nt];
        if (row < N)
          ftb[(size_t)row * HD + w * 64 + nt * 16 + m15] = f2bf(v);
      }
#pragma unroll
      for (int o = 8; o; o >>= 1) {
        v1 += __shfl_xor(v1, o);
        v2 += __shfl_xor(v2, o);
      }
      if (m15 == 0 && row < N) {
        a1[(size_t)row * HEADS + w] = v1;
        a2[(size_t)row * HEADS + w] = v2;
      }
    }
  }
}

// ---------------------------------------------------------------------------
// K3a: per-block partial sums of deg (4 elts/thread, int4 loads)
// ---------------------------------------------------------------------------
__global__ __launch_bounds__(256) void scan_part(
    const int* __restrict__ deg, int* __restrict__ bsum, int n) {
  const int tid = threadIdx.x;
  int base = (blockIdx.x * 256 + tid) * 4;
  int s = 0;
  if (base + 3 < n) {
    int4 v = *(const int4*)&deg[base];
    s = v.x + v.y + v.z + v.w;
  } else {
#pragma unroll
    for (int k = 0; k < 4; ++k)
      if (base + k < n) s += deg[base + k];
  }
#pragma unroll
  for (int o = 32; o; o >>= 1) s += __shfl_xor(s, o);
  __shared__ int ws[4];
  if ((tid & 63) == 0) ws[tid >> 6] = s;
  __syncthreads();
  if (tid == 0) bsum[blockIdx.x] = ws[0] + ws[1] + ws[2] + ws[3];
}

// ---------------------------------------------------------------------------
// K3b: single-wave scan of block sums -> exclusive block offsets + rowptr[n]
// ---------------------------------------------------------------------------
__global__ __launch_bounds__(64) void scan_block(
    const int* __restrict__ bsum, int* __restrict__ boff,
    int* __restrict__ rowptr, int nb, int n) {
  int lane = threadIdx.x;
  int v = (lane < nb) ? bsum[lane] : 0;
  int orig = v;
#pragma unroll
  for (int o = 1; o < 64; o <<= 1) {
    int t = __shfl_up(v, o);
    if (lane >= o) v += t;
  }
  if (lane < nb) boff[lane] = v - orig;
  if (lane == nb - 1) rowptr[n] = v;
}

// ---------------------------------------------------------------------------
// K3c: emit rowptr (block-wide scan over 256 thread sums + int4 stores)
// ---------------------------------------------------------------------------
__global__ __launch_bounds__(256) void scan_emit(
    const int* __restrict__ deg, const int* __restrict__ boff,
    int* __restrict__ rowptr, int n) {
  __shared__ int buf[256];
  const int tid = threadIdx.x;
  int base = (blockIdx.x * 256 + tid) * 4;
  int d0 = 0, d1 = 0, d2 = 0, d3 = 0;
  if (base + 3 < n) {
    int4 v = *(const int4*)&deg[base];
    d0 = v.x; d1 = v.y; d2 = v.z; d3 = v.w;
  } else {
    if (base < n) d0 = deg[base];
    if (base + 1 < n) d1 = deg[base + 1];
    if (base + 2 < n) d2 = deg[base + 2];
    if (base + 3 < n) d3 = deg[base + 3];
  }
  int s = d0 + d1 + d2 + d3;
  buf[tid] = s;
  __syncthreads();
  for (int d = 1; d < 256; d <<= 1) {
    int v = (tid >= d) ? buf[tid - d] : 0;
    __syncthreads();
    buf[tid] += v;
    __syncthreads();
  }
  int excl = buf[tid] - s + boff[blockIdx.x];
  if (base + 3 < n) {
    int4 o;
    o.x = excl;
    o.y = excl + d0;
    o.z = excl + d0 + d1;
    o.w = excl + d0 + d1 + d2;
    *(int4*)&rowptr[base] = o;
  } else {
    int off = excl;
    if (base < n)     { rowptr[base] = off;     off += d0; }
    if (base + 1 < n) { rowptr[base + 1] = off; off += d1; }
    if (base + 2 < n) { rowptr[base + 2] = off; off += d2; }
    if (base + 3 < n) { rowptr[base + 3] = off; }
  }
}

// ---------------------------------------------------------------------------
// K4: CSR scatter of src ids only (scores computed on the fly in K5).
// ---------------------------------------------------------------------------
__global__ __launch_bounds__(256) void edge_scatter_kernel(
    const int* __restrict__ src, const int* __restrict__ dst,
    const int* __restrict__ rowptr, int* __restrict__ cursor,
    int* __restrict__ csr_src, int E) {
  int i = blockIdx.x * blockDim.x + threadIdx.x;
  if (i >= E) return;
  int s_ = src[i], d_ = dst[i];
  int pos = rowptr[d_] + atomicAdd(&cursor[d_], 1);
  csr_src[pos] = s_;
}

// ---------------------------------------------------------------------------
// K5: fused single-pass edge-score + softmax + aggregation + ELU.
// One wave per node. Lane owns 4 output dims (head hg = lane>>4).
// Per edge: src id (wave-broadcast 4B), a1[s,hg] (4B, L2), ft row (uint2).
// e = lrelu(a1[s]+a2[n]); no max shift (|e| bounded; exp fits f32 easily).
// x8 unroll = 8 independent gathers in flight per wave. No LDS.
// ---------------------------------------------------------------------------
__global__ __launch_bounds__(256) void aggregate_kernel(
    const unsigned short* __restrict__ ftb, const float* __restrict__ a1,
    const float* __restrict__ a2, const int* __restrict__ csr_src,
    const int* __restrict__ rowptr, float* __restrict__ out, int N) {
  const int tid = threadIdx.x;
  const int wv = tid >> 6;
  const int lane = tid & 63;
  const int n = blockIdx.x * 4 + wv;
  if (n >= N) return;
  const int hg = lane >> 4;   // head of this lane
  const int start = rowptr[n];
  const int cnt = rowptr[n + 1] - start;
  const float a2n = a2[(size_t)n * HEADS + hg];
  const size_t col = (size_t)(lane * 4);

  float sm = 0.f;
  float a0 = 0.f, b0 = 0.f, c0 = 0.f, d0 = 0.f;
  int j = 0;
  for (; j + 8 <= cnt; j += 8) {
    int s[8];
#pragma unroll
    for (int k = 0; k < 8; ++k) s[k] = csr_src[start + j + k];
    float av[8];
    uint2 u[8];
#pragma unroll
    for (int k = 0; k < 8; ++k) av[k] = a1[(size_t)s[k] * HEADS + hg];
#pragma unroll
    for (int k = 0; k < 8; ++k)
      u[k] = *(const uint2*)&ftb[(size_t)s[k] * HD + col];
#pragma unroll
    for (int k = 0; k < 8; ++k) {
      float ex = __expf(lrelu(av[k] + a2n));
      sm += ex;
      a0 += ex * bflo(u[k].x); b0 += ex * bfhi(u[k].x);
      c0 += ex * bflo(u[k].y); d0 += ex * bfhi(u[k].y);
    }
  }
  for (; j < cnt; ++j) {
    int s = csr_src[start + j];
    float ex = __expf(lrelu(a1[(size_t)s * HEADS + hg] + a2n));
    uint2 u = *(const uint2*)&ftb[(size_t)s * HD + col];
    sm += ex;
    a0 += ex * bflo(u.x); b0 += ex * bfhi(u.x);
    c0 += ex * bflo(u.y); d0 += ex * bfhi(u.y);
  }
  float inv = (cnt > 0) ? 1.f / sm : 0.f;
  a0 *= inv; b0 *= inv; c0 *= inv; d0 *= inv;
  float4 o4;
  o4.x = a0 > 0.f ? a0 : (__expf(a0) - 1.f);
  o4.y = b0 > 0.f ? b0 : (__expf(b0) - 1.f);
  o4.z = c0 > 0.f ? c0 : (__expf(c0) - 1.f);
  o4.w = d0 > 0.f ? d0 : (__expf(d0) - 1.f);
  *(float4*)&out[(size_t)n * HD + col] = o4;
}

// ---------------------------------------------------------------------------
extern "C" void kernel_launch(void* const* d_in, const int* in_sizes, int n_in,
                              void* d_out, int out_size, void* d_ws, size_t ws_size,
                              hipStream_t stream) {
  const float* feat   = (const float*)d_in[0];
  const int*   src    = (const int*)d_in[1];
  const int*   dst    = (const int*)d_in[2];
  const float* W      = (const float*)d_in[3];
  const float* attn_l = (const float*)d_in[4];
  const float* attn_r = (const float*)d_in[5];
  float* out = (float*)d_out;

  const int N = in_sizes[0] / IN_DIM;   // 50000
  const int E = in_sizes[1];            // 800000

  size_t off = 0;
  auto alloc = [&](size_t bytes) -> void* {
    void* p = (char*)d_ws + off;
    off = (off + bytes + 255) & ~(size_t)255;
    return p;
  };
  unsigned short* ftb = (unsigned short*)alloc((size_t)N * HD * 2);
  uint4* whi     = (uint4*)alloc((size_t)HD * IN_DIM * 2);
  uint4* wlo     = (uint4*)alloc((size_t)HD * IN_DIM * 2);
  float* a1      = (float*)alloc((size_t)N * HEADS * 4);
  float* a2      = (float*)alloc((size_t)N * HEADS * 4);
  int*   csr_src = (int*)alloc((size_t)E * 4);
  int*   deg     = (int*)alloc((size_t)2 * N * 4);   // deg + cursor
  int*   cursor  = deg + N;
  int*   rowptr  = (int*)alloc((size_t)(N + 1) * 4);
  int*   bsum    = (int*)alloc(64 * 4);
  int*   boff    = (int*)alloc(64 * 4);
  (void)ws_size;

  hipMemsetAsync(deg, 0, (size_t)2 * N * 4, stream);

  const int eb = (E + 255) / 256;
  const int nb = (N + 1023) / 1024;   // scan blocks (<= 64)
  wcvt_kernel<<<32, 256, 0, stream>>>(W, whi, wlo);
  deg_kernel<<<eb, 256, 0, stream>>>(dst, deg, E);
  scan_part<<<nb, 256, 0, stream>>>(deg, bsum, N);
  scan_block<<<1, 64, 0, stream>>>(bsum, boff, rowptr, nb, N);
  scan_emit<<<nb, 256, 0, stream>>>(deg, boff, rowptr, N);
  gemm_mfma<<<(N + 31) / 32, 256, 0, stream>>>(feat, whi, wlo, attn_l, attn_r,
                                               ftb, a1, a2, N);
  edge_scatter_kernel<<<eb, 256, 0, stream>>>(src, dst, rowptr, cursor,
                                              csr_src, E);
  aggregate_kernel<<<(N + 3) / 4, 256, 0, stream>>>(ftb, a1, a2, csr_src,
                                                    rowptr, out, N);
}

// Round 11
// 189.403 us; speedup vs baseline: 1.6585x; 1.0434x over previous
//
#include <hip/hip_runtime.h>
#include <hip/hip_bf16.h>

#define ALPHA 0.2f
#define IN_DIM 256
#define HD 256      // HEADS*OUT_DIM
#define HEADS 4

typedef short short8 __attribute__((ext_vector_type(8)));
typedef float f32x4 __attribute__((ext_vector_type(4)));

__device__ __forceinline__ float lrelu(float x) { return x > 0.f ? x : ALPHA * x; }

__device__ __forceinline__ unsigned short f2bf(float x) {  // RTNE f32->bf16
  unsigned int u = __builtin_bit_cast(unsigned int, x);
  unsigned int r = (u + 0x7fffu + ((u >> 16) & 1u)) >> 16;
  return (unsigned short)r;
}
__device__ __forceinline__ float bf2f(unsigned short h) {
  unsigned int u = ((unsigned int)h) << 16;
  return __builtin_bit_cast(float, u);
}
// packed bf16 pair -> f32 (low / high element)
__device__ __forceinline__ float bflo(unsigned int u) {
  return __builtin_bit_cast(float, u << 16);
}
__device__ __forceinline__ float bfhi(unsigned int u) {
  return __builtin_bit_cast(float, u & 0xffff0000u);
}
// split-precision pair conversion (manual RTNE, trivially-copyable types):
// hi = pack(bf16(x), bf16(y)); lo = pack(bf16(x-hi.x), bf16(y-hi.y)).
__device__ __forceinline__ void cvt2(float x, float y, unsigned int& hi,
                                     unsigned int& lo) {
  unsigned short hx = f2bf(x), hy = f2bf(y);
  hi = (unsigned int)hx | ((unsigned int)hy << 16);
  unsigned short lx = f2bf(x - bf2f(hx)), ly = f2bf(y - bf2f(hy));
  lo = (unsigned int)lx | ((unsigned int)ly << 16);
}

// ---------------------------------------------------------------------------
// K0: W (f32 [256][256]) -> hi/lo bf16, PERMUTED into MFMA-fragment order:
//   uint4 dst idx = (((head*8+ks)*4+nt)*4+g)*16 + m15
// ---------------------------------------------------------------------------
__global__ __launch_bounds__(256) void wcvt_kernel(
    const float* __restrict__ W, uint4* __restrict__ whi,
    uint4* __restrict__ wlo) {
  int u = blockIdx.x * 256 + threadIdx.x;   // source uint4 index
  int n = u >> 5, c = u & 31;               // row, k-chunk
  int ks = c >> 2, g = c & 3;
  int head = n >> 6, nt = (n >> 4) & 3, m15 = n & 15;
  const float* gp = &W[(size_t)u * 8];
  float4 f0 = *(const float4*)gp;
  float4 f1 = *(const float4*)(gp + 4);
  uint4 ph, pl;
  cvt2(f0.x, f0.y, ph.x, pl.x);
  cvt2(f0.z, f0.w, ph.y, pl.y);
  cvt2(f1.x, f1.y, ph.z, pl.z);
  cvt2(f1.z, f1.w, ph.w, pl.w);
  int dst = (((head * 8 + ks) * 4 + nt) * 4 + g) * 16 + m15;
  whi[dst] = ph;
  wlo[dst] = pl;
}

// ---------------------------------------------------------------------------
// K1: merged [deg histogram || split-precision MFMA projection].
// Blocks [0, DB): degree histogram (latency-bound atomics, overlapped).
// Blocks [DB, DB+GB): gemm, M-tile 32 rows, wave w owns head w.
// ---------------------------------------------------------------------------
__global__ __launch_bounds__(256, 4) void gemm_deg_kernel(
    const float* __restrict__ feat, const uint4* __restrict__ whi,
    const uint4* __restrict__ wlo,
    const float* __restrict__ attn_l, const float* __restrict__ attn_r,
    unsigned short* __restrict__ ftb, float* __restrict__ a1,
    float* __restrict__ a2, int N,
    const int* __restrict__ edst, int* __restrict__ deg, int E, int DB) {
  __shared__ uint4 ldsh[1024];  // A-hi: 32 rows x 512B, swizzled
  __shared__ uint4 ldsl[1024];  // A-lo
  const int tid = threadIdx.x;

  if ((int)blockIdx.x < DB) {   // ---- degree histogram path ----
    int b = (blockIdx.x * 256 + tid) * 4;
    if (b + 3 < E) {
      int4 d4 = *(const int4*)&edst[b];
      atomicAdd(&deg[d4.x], 1);
      atomicAdd(&deg[d4.y], 1);
      atomicAdd(&deg[d4.z], 1);
      atomicAdd(&deg[d4.w], 1);
    } else {
#pragma unroll
      for (int k = 0; k < 4; ++k)
        if (b + k < E) atomicAdd(&deg[edst[b + k]], 1);
    }
    return;
  }

  // ---- gemm path ----
  const int row0 = (blockIdx.x - DB) * 32;

#pragma unroll
  for (int it = 0; it < 4; ++it) {
    int ci = tid + it * 256;
    int row = ci >> 5, c16 = ci & 31;
    int grow = row0 + row;
    uint4 ph = uint4{0u, 0u, 0u, 0u}, pl = uint4{0u, 0u, 0u, 0u};
    if (grow < N) {
      const float* gp = &feat[(size_t)grow * IN_DIM + c16 * 8];
      float4 f0 = *(const float4*)gp;
      float4 f1 = *(const float4*)(gp + 4);
      cvt2(f0.x, f0.y, ph.x, pl.x);
      cvt2(f0.z, f0.w, ph.y, pl.y);
      cvt2(f1.x, f1.y, ph.z, pl.z);
      cvt2(f1.z, f1.w, ph.w, pl.w);
    }
    int idx = (row * 512 + ((c16 * 16) ^ ((row & 7) << 4))) >> 4;
    ldsh[idx] = ph;
    ldsl[idx] = pl;
  }
  __syncthreads();

  const int lane = tid & 63;
  const int w = tid >> 6;   // wave id == head id == N-quadrant
  const int m15 = lane & 15;
  const int g = lane >> 4;  // k-group 0..3

  f32x4 acc[2][4];
#pragma unroll
  for (int mt = 0; mt < 2; ++mt)
#pragma unroll
    for (int nt = 0; nt < 4; ++nt) acc[mt][nt] = f32x4{0.f, 0.f, 0.f, 0.f};

  for (int ks = 0; ks < 8; ++ks) {       // K = 8 * 32
    short8 ah[2], al_[2], bh[4], bl[4];
#pragma unroll
    for (int mt = 0; mt < 2; ++mt) {
      int row = mt * 16 + m15;
      int idx = (row * 512 + ((ks * 64 + g * 16) ^ ((row & 7) << 4))) >> 4;
      ah[mt] = __builtin_bit_cast(short8, ldsh[idx]);
      al_[mt] = __builtin_bit_cast(short8, ldsl[idx]);
    }
#pragma unroll
    for (int nt = 0; nt < 4; ++nt) {
      int idx = (((w * 8 + ks) * 4 + nt) * 4 + g) * 16 + m15;
      bh[nt] = __builtin_bit_cast(short8, whi[idx]);
      bl[nt] = __builtin_bit_cast(short8, wlo[idx]);
    }
#pragma unroll
    for (int mt = 0; mt < 2; ++mt)
#pragma unroll
      for (int nt = 0; nt < 4; ++nt) {
        acc[mt][nt] = __builtin_amdgcn_mfma_f32_16x16x32_bf16(
            ah[mt], bh[nt], acc[mt][nt], 0, 0, 0);
        acc[mt][nt] = __builtin_amdgcn_mfma_f32_16x16x32_bf16(
            ah[mt], bl[nt], acc[mt][nt], 0, 0, 0);
        acc[mt][nt] = __builtin_amdgcn_mfma_f32_16x16x32_bf16(
            al_[mt], bh[nt], acc[mt][nt], 0, 0, 0);
      }
  }

  // epilogue: ft (bf16) + fused a1/a2 (f32)
  float al[4], ar[4];
#pragma unroll
  for (int nt = 0; nt < 4; ++nt) {
    al[nt] = attn_l[w * 64 + nt * 16 + m15];
    ar[nt] = attn_r[w * 64 + nt * 16 + m15];
  }
#pragma unroll
  for (int mt = 0; mt < 2; ++mt) {
#pragma unroll
    for (int r = 0; r < 4; ++r) {
      int rloc = mt * 16 + g * 4 + r;  // C/D: row=(lane>>4)*4+reg (m89)
      int row = row0 + rloc;
      float v1 = 0.f, v2 = 0.f;
#pragma unroll
      for (int nt = 0; nt < 4; ++nt) {
        float v = acc[mt][nt][r];
        v1 += v * al[nt];
        v2 += v * ar[nt];
        if (row < N)
          ftb[(size_t)row * HD + w * 64 + nt * 16 + m15] = f2bf(v);
      }
#pragma unroll
      for (int o = 8; o; o >>= 1) {
        v1 += __shfl_xor(v1, o);
        v2 += __shfl_xor(v2, o);
      }
      if (m15 == 0 && row < N) {
        a1[(size_t)row * HEADS + w] = v1;
        a2[(size_t)row * HEADS + w] = v2;
      }
    }
  }
}

// ---------------------------------------------------------------------------
// K3a: per-block partial sums of deg (4 elts/thread, int4 loads)
// ---------------------------------------------------------------------------
__global__ __launch_bounds__(256) void scan_part(
    const int* __restrict__ deg, int* __restrict__ bsum, int n) {
  const int tid = threadIdx.x;
  int base = (blockIdx.x * 256 + tid) * 4;
  int s = 0;
  if (base + 3 < n) {
    int4 v = *(const int4*)&deg[base];
    s = v.x + v.y + v.z + v.w;
  } else {
#pragma unroll
    for (int k = 0; k < 4; ++k)
      if (base + k < n) s += deg[base + k];
  }
#pragma unroll
  for (int o = 32; o; o >>= 1) s += __shfl_xor(s, o);
  __shared__ int ws[4];
  if ((tid & 63) == 0) ws[tid >> 6] = s;
  __syncthreads();
  if (tid == 0) bsum[blockIdx.x] = ws[0] + ws[1] + ws[2] + ws[3];
}

// ---------------------------------------------------------------------------
// K3b: single-wave scan of block sums -> exclusive block offsets + rowptr[n]
// ---------------------------------------------------------------------------
__global__ __launch_bounds__(64) void scan_block(
    const int* __restrict__ bsum, int* __restrict__ boff,
    int* __restrict__ rowptr, int nb, int n) {
  int lane = threadIdx.x;
  int v = (lane < nb) ? bsum[lane] : 0;
  int orig = v;
#pragma unroll
  for (int o = 1; o < 64; o <<= 1) {
    int t = __shfl_up(v, o);
    if (lane >= o) v += t;
  }
  if (lane < nb) boff[lane] = v - orig;
  if (lane == nb - 1) rowptr[n] = v;
}

// ---------------------------------------------------------------------------
// K3c: emit rowptr (block-wide scan over 256 thread sums + int4 stores)
// ---------------------------------------------------------------------------
__global__ __launch_bounds__(256) void scan_emit(
    const int* __restrict__ deg, const int* __restrict__ boff,
    int* __restrict__ rowptr, int n) {
  __shared__ int buf[256];
  const int tid = threadIdx.x;
  int base = (blockIdx.x * 256 + tid) * 4;
  int d0 = 0, d1 = 0, d2 = 0, d3 = 0;
  if (base + 3 < n) {
    int4 v = *(const int4*)&deg[base];
    d0 = v.x; d1 = v.y; d2 = v.z; d3 = v.w;
  } else {
    if (base < n) d0 = deg[base];
    if (base + 1 < n) d1 = deg[base + 1];
    if (base + 2 < n) d2 = deg[base + 2];
    if (base + 3 < n) d3 = deg[base + 3];
  }
  int s = d0 + d1 + d2 + d3;
  buf[tid] = s;
  __syncthreads();
  for (int d = 1; d < 256; d <<= 1) {
    int v = (tid >= d) ? buf[tid - d] : 0;
    __syncthreads();
    buf[tid] += v;
    __syncthreads();
  }
  int excl = buf[tid] - s + boff[blockIdx.x];
  if (base + 3 < n) {
    int4 o;
    o.x = excl;
    o.y = excl + d0;
    o.z = excl + d0 + d1;
    o.w = excl + d0 + d1 + d2;
    *(int4*)&rowptr[base] = o;
  } else {
    int off = excl;
    if (base < n)     { rowptr[base] = off;     off += d0; }
    if (base + 1 < n) { rowptr[base + 1] = off; off += d1; }
    if (base + 2 < n) { rowptr[base + 2] = off; off += d2; }
    if (base + 3 < n) { rowptr[base + 3] = off; }
  }
}

// ---------------------------------------------------------------------------
// K4: CSR scatter of src ids (4 edges/thread, int4 loads).
// ---------------------------------------------------------------------------
__global__ __launch_bounds__(256) void edge_scatter_kernel(
    const int* __restrict__ src, const int* __restrict__ dst,
    const int* __restrict__ rowptr, int* __restrict__ cursor,
    int* __restrict__ csr_src, int E) {
  int base = (blockIdx.x * 256 + threadIdx.x) * 4;
  if (base >= E) return;
  if (base + 3 < E) {
    int4 s4 = *(const int4*)&src[base];
    int4 d4 = *(const int4*)&dst[base];
    int ss[4] = {s4.x, s4.y, s4.z, s4.w};
    int dd[4] = {d4.x, d4.y, d4.z, d4.w};
#pragma unroll
    for (int k = 0; k < 4; ++k) {
      int pos = rowptr[dd[k]] + atomicAdd(&cursor[dd[k]], 1);
      csr_src[pos] = ss[k];
    }
  } else {
    for (int k = 0; k < 4 && base + k < E; ++k) {
      int d_ = dst[base + k];
      int pos = rowptr[d_] + atomicAdd(&cursor[d_], 1);
      csr_src[pos] = src[base + k];
    }
  }
}

// ---------------------------------------------------------------------------
// K5: fused single-pass edge-score + softmax + aggregation + ELU.
// One wave per node; lane owns 4 output dims (head hg = lane>>4).
// All gathers use uniform-base + 32-bit byte offset (SADDR form).
// ---------------------------------------------------------------------------
__global__ __launch_bounds__(256) void aggregate_kernel(
    const unsigned short* __restrict__ ftb, const float* __restrict__ a1,
    const float* __restrict__ a2, const int* __restrict__ csr_src,
    const int* __restrict__ rowptr, float* __restrict__ out, int N) {
  const int tid = threadIdx.x;
  const int wv = tid >> 6;
  const int lane = tid & 63;
  const int n = blockIdx.x * 4 + wv;
  if (n >= N) return;
  const int hg = lane >> 4;   // head of this lane
  const int start = rowptr[n];
  const int cnt = rowptr[n + 1] - start;
  const float a2n = a2[n * HEADS + hg];
  const unsigned colB = (unsigned)(lane * 8);      // byte off of lane's 8B
  const unsigned hgB = (unsigned)(hg << 2);
  const char* ftB = (const char*)ftb;
  const char* a1B = (const char*)a1;

  float sm = 0.f;
  float a0 = 0.f, b0 = 0.f, c0 = 0.f, d0 = 0.f;
  int j = 0;
  for (; j + 8 <= cnt; j += 8) {
    int s[8];
#pragma unroll
    for (int k = 0; k < 8; ++k) s[k] = csr_src[start + j + k];
    float av[8];
    uint2 u[8];
#pragma unroll
    for (int k = 0; k < 8; ++k)
      av[k] = *(const float*)(a1B + (((unsigned)s[k] << 4) + hgB));
#pragma unroll
    for (int k = 0; k < 8; ++k)
      u[k] = *(const uint2*)(ftB + (((unsigned)s[k] << 9) + colB));
#pragma unroll
    for (int k = 0; k < 8; ++k) {
      float ex = __expf(lrelu(av[k] + a2n));
      sm += ex;
      a0 += ex * bflo(u[k].x); b0 += ex * bfhi(u[k].x);
      c0 += ex * bflo(u[k].y); d0 += ex * bfhi(u[k].y);
    }
  }
  for (; j < cnt; ++j) {
    int s = csr_src[start + j];
    float ex = __expf(lrelu(*(const float*)(a1B + (((unsigned)s << 4) + hgB))
                            + a2n));
    uint2 u = *(const uint2*)(ftB + (((unsigned)s << 9) + colB));
    sm += ex;
    a0 += ex * bflo(u.x); b0 += ex * bfhi(u.x);
    c0 += ex * bflo(u.y); d0 += ex * bfhi(u.y);
  }
  float inv = (cnt > 0) ? 1.f / sm : 0.f;
  a0 *= inv; b0 *= inv; c0 *= inv; d0 *= inv;
  float4 o4;
  o4.x = a0 > 0.f ? a0 : (__expf(a0) - 1.f);
  o4.y = b0 > 0.f ? b0 : (__expf(b0) - 1.f);
  o4.z = c0 > 0.f ? c0 : (__expf(c0) - 1.f);
  o4.w = d0 > 0.f ? d0 : (__expf(d0) - 1.f);
  *(float4*)&out[(size_t)n * HD + (size_t)(lane * 4)] = o4;
}

// ---------------------------------------------------------------------------
extern "C" void kernel_launch(void* const* d_in, const int* in_sizes, int n_in,
                              void* d_out, int out_size, void* d_ws, size_t ws_size,
                              hipStream_t stream) {
  const float* feat   = (const float*)d_in[0];
  const int*   src    = (const int*)d_in[1];
  const int*   dst    = (const int*)d_in[2];
  const float* W      = (const float*)d_in[3];
  const float* attn_l = (const float*)d_in[4];
  const float* attn_r = (const float*)d_in[5];
  float* out = (float*)d_out;

  const int N = in_sizes[0] / IN_DIM;   // 50000
  const int E = in_sizes[1];            // 800000

  size_t off = 0;
  auto alloc = [&](size_t bytes) -> void* {
    void* p = (char*)d_ws + off;
    off = (off + bytes + 255) & ~(size_t)255;
    return p;
  };
  unsigned short* ftb = (unsigned short*)alloc((size_t)N * HD * 2);
  uint4* whi     = (uint4*)alloc((size_t)HD * IN_DIM * 2);
  uint4* wlo     = (uint4*)alloc((size_t)HD * IN_DIM * 2);
  float* a1      = (float*)alloc((size_t)N * HEADS * 4);
  float* a2      = (float*)alloc((size_t)N * HEADS * 4);
  int*   csr_src = (int*)alloc((size_t)E * 4);
  int*   deg     = (int*)alloc((size_t)2 * N * 4);   // deg + cursor
  int*   cursor  = deg + N;
  int*   rowptr  = (int*)alloc((size_t)(N + 1) * 4);
  int*   bsum    = (int*)alloc(64 * 4);
  int*   boff    = (int*)alloc(64 * 4);
  (void)ws_size;

  (void)hipMemsetAsync(deg, 0, (size_t)2 * N * 4, stream);

  const int DB = (E + 1023) / 1024;   // deg blocks (4 edges/thread)
  const int GB = (N + 31) / 32;       // gemm blocks
  const int nb = (N + 1023) / 1024;   // scan blocks (<= 64)
  wcvt_kernel<<<32, 256, 0, stream>>>(W, whi, wlo);
  gemm_deg_kernel<<<DB + GB, 256, 0, stream>>>(feat, whi, wlo, attn_l, attn_r,
                                               ftb, a1, a2, N, dst, deg, E, DB);
  scan_part<<<nb, 256, 0, stream>>>(deg, bsum, N);
  scan_block<<<1, 64, 0, stream>>>(bsum, boff, rowptr, nb, N);
  scan_emit<<<nb, 256, 0, stream>>>(deg, boff, rowptr, N);
  edge_scatter_kernel<<<(E + 1023) / 1024, 256, 0, stream>>>(
      src, dst, rowptr, cursor, csr_src, E);
  aggregate_kernel<<<(N + 3) / 4, 256, 0, stream>>>(ftb, a1, a2, csr_src,
                                                    rowptr, out, N);
}

// Round 13
// 184.563 us; speedup vs baseline: 1.7020x; 1.0262x over previous
//
#include <hip/hip_runtime.h>
#include <hip/hip_bf16.h>

#define ALPHA 0.2f
#define IN_DIM 256
#define HD 256      // HEADS*OUT_DIM
#define HEADS 4

typedef _Float16 half8 __attribute__((ext_vector_type(8)));
typedef __fp16 fp16x2 __attribute__((ext_vector_type(2)));
typedef float f32x4 __attribute__((ext_vector_type(4)));

__device__ __forceinline__ float lrelu(float x) { return x > 0.f ? x : ALPHA * x; }

__device__ __forceinline__ unsigned short f2bf(float x) {  // RTNE f32->bf16
  unsigned int u = __builtin_bit_cast(unsigned int, x);
  unsigned int r = (u + 0x7fffu + ((u >> 16) & 1u)) >> 16;
  return (unsigned short)r;
}
// packed bf16 pair -> f32 (low / high element)
__device__ __forceinline__ float bflo(unsigned int u) {
  return __builtin_bit_cast(float, u << 16);
}
__device__ __forceinline__ float bfhi(unsigned int u) {
  return __builtin_bit_cast(float, u & 0xffff0000u);
}
// pack 2 f32 -> 2 fp16 (RTZ, single v_cvt_pkrtz_f16_f32)
__device__ __forceinline__ unsigned int pk16(float x, float y) {
  fp16x2 h = __builtin_amdgcn_cvt_pkrtz(x, y);
  return __builtin_bit_cast(unsigned int, h);
}

// ---------------------------------------------------------------------------
// K0: W (f32 [256][256]) -> fp16, PERMUTED into MFMA-fragment order:
//   uint4 dst idx = (((head*8+ks)*4+nt)*4+g)*16 + m15
// so a wave's B-fragment load (lane = g*16+m15) is one contiguous 1KB line.
// ---------------------------------------------------------------------------
__global__ __launch_bounds__(256) void wcvt_kernel(
    const float* __restrict__ W, uint4* __restrict__ wfp) {
  int u = blockIdx.x * 256 + threadIdx.x;   // source 8-float group index
  int n = u >> 5, c = u & 31;               // row, k-chunk
  int ks = c >> 2, g = c & 3;
  int head = n >> 6, nt = (n >> 4) & 3, m15 = n & 15;
  const float* gp = &W[(size_t)u * 8];
  float4 f0 = *(const float4*)gp;
  float4 f1 = *(const float4*)(gp + 4);
  uint4 p;
  p.x = pk16(f0.x, f0.y);
  p.y = pk16(f0.z, f0.w);
  p.z = pk16(f1.x, f1.y);
  p.w = pk16(f1.z, f1.w);
  int dst = (((head * 8 + ks) * 4 + nt) * 4 + g) * 16 + m15;
  wfp[dst] = p;
}

// ---------------------------------------------------------------------------
// K1: merged [deg histogram || fp16 MFMA projection].
// Blocks [0, DB): degree histogram (latency-bound atomics, overlapped).
// Blocks [DB, DB+GB): gemm, M-tile 32 rows, wave w owns head w.
// Single fp16 MFMA per fragment (f32 accumulate) — fp16's 11 mantissa bits
// give ~5e-3 score error (vs bf16's 4e-2 which failed round 2).
// ---------------------------------------------------------------------------
__global__ __launch_bounds__(256, 4) void gemm_deg_kernel(
    const float* __restrict__ feat, const uint4* __restrict__ wfp,
    const float* __restrict__ attn_l, const float* __restrict__ attn_r,
    unsigned short* __restrict__ ftb, float* __restrict__ a1,
    float* __restrict__ a2, int N,
    const int* __restrict__ edst, int* __restrict__ deg, int E, int DB) {
  __shared__ uint4 lds[1024];   // A: 32 rows x 512B (fp16), XOR-swizzled
  const int tid = threadIdx.x;

  if ((int)blockIdx.x < DB) {   // ---- degree histogram path ----
    int b = (blockIdx.x * 256 + tid) * 4;
    if (b + 3 < E) {
      int4 d4 = *(const int4*)&edst[b];
      atomicAdd(&deg[d4.x], 1);
      atomicAdd(&deg[d4.y], 1);
      atomicAdd(&deg[d4.z], 1);
      atomicAdd(&deg[d4.w], 1);
    } else {
#pragma unroll
      for (int k = 0; k < 4; ++k)
        if (b + k < E) atomicAdd(&deg[edst[b + k]], 1);
    }
    return;
  }

  // ---- gemm path ----
  const int row0 = (blockIdx.x - DB) * 32;

#pragma unroll
  for (int it = 0; it < 4; ++it) {
    int ci = tid + it * 256;
    int row = ci >> 5, c16 = ci & 31;
    int grow = row0 + row;
    uint4 p = uint4{0u, 0u, 0u, 0u};
    if (grow < N) {
      const float* gp = &feat[(size_t)grow * IN_DIM + c16 * 8];
      float4 f0 = *(const float4*)gp;
      float4 f1 = *(const float4*)(gp + 4);
      p.x = pk16(f0.x, f0.y);
      p.y = pk16(f0.z, f0.w);
      p.z = pk16(f1.x, f1.y);
      p.w = pk16(f1.z, f1.w);
    }
    int idx = (row * 512 + ((c16 * 16) ^ ((row & 7) << 4))) >> 4;
    lds[idx] = p;
  }
  __syncthreads();

  const int lane = tid & 63;
  const int w = tid >> 6;   // wave id == head id == N-quadrant
  const int m15 = lane & 15;
  const int g = lane >> 4;  // k-group 0..3

  f32x4 acc[2][4];
#pragma unroll
  for (int mt = 0; mt < 2; ++mt)
#pragma unroll
    for (int nt = 0; nt < 4; ++nt) acc[mt][nt] = f32x4{0.f, 0.f, 0.f, 0.f};

  for (int ks = 0; ks < 8; ++ks) {       // K = 8 * 32
    half8 ah[2], bh[4];
#pragma unroll
    for (int mt = 0; mt < 2; ++mt) {
      int row = mt * 16 + m15;
      int idx = (row * 512 + ((ks * 64 + g * 16) ^ ((row & 7) << 4))) >> 4;
      ah[mt] = __builtin_bit_cast(half8, lds[idx]);
    }
#pragma unroll
    for (int nt = 0; nt < 4; ++nt) {
      int idx = (((w * 8 + ks) * 4 + nt) * 4 + g) * 16 + m15;
      bh[nt] = __builtin_bit_cast(half8, wfp[idx]);
    }
#pragma unroll
    for (int mt = 0; mt < 2; ++mt)
#pragma unroll
      for (int nt = 0; nt < 4; ++nt)
        acc[mt][nt] = __builtin_amdgcn_mfma_f32_16x16x32_f16(
            ah[mt], bh[nt], acc[mt][nt], 0, 0, 0);
  }

  // epilogue: ft (bf16) + fused a1/a2 (f32)
  float al[4], ar[4];
#pragma unroll
  for (int nt = 0; nt < 4; ++nt) {
    al[nt] = attn_l[w * 64 + nt * 16 + m15];
    ar[nt] = attn_r[w * 64 + nt * 16 + m15];
  }
#pragma unroll
  for (int mt = 0; mt < 2; ++mt) {
#pragma unroll
    for (int r = 0; r < 4; ++r) {
      int rloc = mt * 16 + g * 4 + r;  // C/D: row=(lane>>4)*4+reg (m89)
      int row = row0 + rloc;
      float v1 = 0.f, v2 = 0.f;
#pragma unroll
      for (int nt = 0; nt < 4; ++nt) {
        float v = acc[mt][nt][r];
        v1 += v * al[nt];
        v2 += v * ar[nt];
        if (row < N)
          ftb[(size_t)row * HD + w * 64 + nt * 16 + m15] = f2bf(v);
      }
#pragma unroll
      for (int o = 8; o; o >>= 1) {
        v1 += __shfl_xor(v1, o);
        v2 += __shfl_xor(v2, o);
      }
      if (m15 == 0 && row < N) {
        a1[(size_t)row * HEADS + w] = v1;
        a2[(size_t)row * HEADS + w] = v2;
      }
    }
  }
}

// ---------------------------------------------------------------------------
// K3a: per-block partial sums of deg (4 elts/thread, int4 loads)
// ---------------------------------------------------------------------------
__global__ __launch_bounds__(256) void scan_part(
    const int* __restrict__ deg, int* __restrict__ bsum, int n) {
  const int tid = threadIdx.x;
  int base = (blockIdx.x * 256 + tid) * 4;
  int s = 0;
  if (base + 3 < n) {
    int4 v = *(const int4*)&deg[base];
    s = v.x + v.y + v.z + v.w;
  } else {
#pragma unroll
    for (int k = 0; k < 4; ++k)
      if (base + k < n) s += deg[base + k];
  }
#pragma unroll
  for (int o = 32; o; o >>= 1) s += __shfl_xor(s, o);
  __shared__ int ws[4];
  if ((tid & 63) == 0) ws[tid >> 6] = s;
  __syncthreads();
  if (tid == 0) bsum[blockIdx.x] = ws[0] + ws[1] + ws[2] + ws[3];
}

// ---------------------------------------------------------------------------
// K3b: single-wave scan of block sums -> exclusive block offsets + rowptr[n]
// ---------------------------------------------------------------------------
__global__ __launch_bounds__(64) void scan_block(
    const int* __restrict__ bsum, int* __restrict__ boff,
    int* __restrict__ rowptr, int nb, int n) {
  int lane = threadIdx.x;
  int v = (lane < nb) ? bsum[lane] : 0;
  int orig = v;
#pragma unroll
  for (int o = 1; o < 64; o <<= 1) {
    int t = __shfl_up(v, o);
    if (lane >= o) v += t;
  }
  if (lane < nb) boff[lane] = v - orig;
  if (lane == nb - 1) rowptr[n] = v;
}

// ---------------------------------------------------------------------------
// K3c: emit rowptr (block-wide scan over 256 thread sums + int4 stores)
// ---------------------------------------------------------------------------
__global__ __launch_bounds__(256) void scan_emit(
    const int* __restrict__ deg, const int* __restrict__ boff,
    int* __restrict__ rowptr, int n) {
  __shared__ int buf[256];
  const int tid = threadIdx.x;
  int base = (blockIdx.x * 256 + tid) * 4;
  int d0 = 0, d1 = 0, d2 = 0, d3 = 0;
  if (base + 3 < n) {
    int4 v = *(const int4*)&deg[base];
    d0 = v.x; d1 = v.y; d2 = v.z; d3 = v.w;
  } else {
    if (base < n) d0 = deg[base];
    if (base + 1 < n) d1 = deg[base + 1];
    if (base + 2 < n) d2 = deg[base + 2];
    if (base + 3 < n) d3 = deg[base + 3];
  }
  int s = d0 + d1 + d2 + d3;
  buf[tid] = s;
  __syncthreads();
  for (int d = 1; d < 256; d <<= 1) {
    int v = (tid >= d) ? buf[tid - d] : 0;
    __syncthreads();
    buf[tid] += v;
    __syncthreads();
  }
  int excl = buf[tid] - s + boff[blockIdx.x];
  if (base + 3 < n) {
    int4 o;
    o.x = excl;
    o.y = excl + d0;
    o.z = excl + d0 + d1;
    o.w = excl + d0 + d1 + d2;
    *(int4*)&rowptr[base] = o;
  } else {
    int off = excl;
    if (base < n)     { rowptr[base] = off;     off += d0; }
    if (base + 1 < n) { rowptr[base + 1] = off; off += d1; }
    if (base + 2 < n) { rowptr[base + 2] = off; off += d2; }
    if (base + 3 < n) { rowptr[base + 3] = off; }
  }
}

// ---------------------------------------------------------------------------
// K4: CSR scatter of src ids (4 edges/thread, int4 loads).
// ---------------------------------------------------------------------------
__global__ __launch_bounds__(256) void edge_scatter_kernel(
    const int* __restrict__ src, const int* __restrict__ dst,
    const int* __restrict__ rowptr, int* __restrict__ cursor,
    int* __restrict__ csr_src, int E) {
  int base = (blockIdx.x * 256 + threadIdx.x) * 4;
  if (base >= E) return;
  if (base + 3 < E) {
    int4 s4 = *(const int4*)&src[base];
    int4 d4 = *(const int4*)&dst[base];
    int ss[4] = {s4.x, s4.y, s4.z, s4.w};
    int dd[4] = {d4.x, d4.y, d4.z, d4.w};
#pragma unroll
    for (int k = 0; k < 4; ++k) {
      int pos = rowptr[dd[k]] + atomicAdd(&cursor[dd[k]], 1);
      csr_src[pos] = ss[k];
    }
  } else {
    for (int k = 0; k < 4 && base + k < E; ++k) {
      int d_ = dst[base + k];
      int pos = rowptr[d_] + atomicAdd(&cursor[d_], 1);
      csr_src[pos] = src[base + k];
    }
  }
}

// ---------------------------------------------------------------------------
// K5: fused single-pass edge-score + softmax + aggregation + ELU.
// One wave per node; lane owns 4 output dims (head hg = lane>>4).
// All gathers use uniform-base + 32-bit byte offset (SADDR form).
// ---------------------------------------------------------------------------
__global__ __launch_bounds__(256) void aggregate_kernel(
    const unsigned short* __restrict__ ftb, const float* __restrict__ a1,
    const float* __restrict__ a2, const int* __restrict__ csr_src,
    const int* __restrict__ rowptr, float* __restrict__ out, int N) {
  const int tid = threadIdx.x;
  const int wv = tid >> 6;
  const int lane = tid & 63;
  const int n = blockIdx.x * 4 + wv;
  if (n >= N) return;
  const int hg = lane >> 4;   // head of this lane
  const int start = rowptr[n];
  const int cnt = rowptr[n + 1] - start;
  const float a2n = a2[n * HEADS + hg];
  const unsigned colB = (unsigned)(lane * 8);      // byte off of lane's 8B
  const unsigned hgB = (unsigned)(hg << 2);
  const char* ftB = (const char*)ftb;
  const char* a1B = (const char*)a1;

  float sm = 0.f;
  float a0 = 0.f, b0 = 0.f, c0 = 0.f, d0 = 0.f;
  int j = 0;
  for (; j + 8 <= cnt; j += 8) {
    int s[8];
#pragma unroll
    for (int k = 0; k < 8; ++k) s[k] = csr_src[start + j + k];
    float av[8];
    uint2 u[8];
#pragma unroll
    for (int k = 0; k < 8; ++k)
      av[k] = *(const float*)(a1B + (((unsigned)s[k] << 4) + hgB));
#pragma unroll
    for (int k = 0; k < 8; ++k)
      u[k] = *(const uint2*)(ftB + (((unsigned)s[k] << 9) + colB));
#pragma unroll
    for (int k = 0; k < 8; ++k) {
      float ex = __expf(lrelu(av[k] + a2n));
      sm += ex;
      a0 += ex * bflo(u[k].x); b0 += ex * bfhi(u[k].x);
      c0 += ex * bflo(u[k].y); d0 += ex * bfhi(u[k].y);
    }
  }
  for (; j < cnt; ++j) {
    int s = csr_src[start + j];
    float ex = __expf(lrelu(*(const float*)(a1B + (((unsigned)s << 4) + hgB))
                            + a2n));
    uint2 u = *(const uint2*)(ftB + (((unsigned)s << 9) + colB));
    sm += ex;
    a0 += ex * bflo(u.x); b0 += ex * bfhi(u.x);
    c0 += ex * bflo(u.y); d0 += ex * bfhi(u.y);
  }
  float inv = (cnt > 0) ? 1.f / sm : 0.f;
  a0 *= inv; b0 *= inv; c0 *= inv; d0 *= inv;
  float4 o4;
  o4.x = a0 > 0.f ? a0 : (__expf(a0) - 1.f);
  o4.y = b0 > 0.f ? b0 : (__expf(b0) - 1.f);
  o4.z = c0 > 0.f ? c0 : (__expf(c0) - 1.f);
  o4.w = d0 > 0.f ? d0 : (__expf(d0) - 1.f);
  *(float4*)&out[(size_t)n * HD + (size_t)(lane * 4)] = o4;
}

// ---------------------------------------------------------------------------
extern "C" void kernel_launch(void* const* d_in, const int* in_sizes, int n_in,
                              void* d_out, int out_size, void* d_ws, size_t ws_size,
                              hipStream_t stream) {
  const float* feat   = (const float*)d_in[0];
  const int*   src    = (const int*)d_in[1];
  const int*   dst    = (const int*)d_in[2];
  const float* W      = (const float*)d_in[3];
  const float* attn_l = (const float*)d_in[4];
  const float* attn_r = (const float*)d_in[5];
  float* out = (float*)d_out;

  const int N = in_sizes[0] / IN_DIM;   // 50000
  const int E = in_sizes[1];            // 800000

  size_t off = 0;
  auto alloc = [&](size_t bytes) -> void* {
    void* p = (char*)d_ws + off;
    off = (off + bytes + 255) & ~(size_t)255;
    return p;
  };
  unsigned short* ftb = (unsigned short*)alloc((size_t)N * HD * 2);
  uint4* wfp     = (uint4*)alloc((size_t)HD * IN_DIM * 2);
  float* a1      = (float*)alloc((size_t)N * HEADS * 4);
  float* a2      = (float*)alloc((size_t)N * HEADS * 4);
  int*   csr_src = (int*)alloc((size_t)E * 4);
  int*   deg     = (int*)alloc((size_t)2 * N * 4);   // deg + cursor
  int*   cursor  = deg + N;
  int*   rowptr  = (int*)alloc((size_t)(N + 1) * 4);
  int*   bsum    = (int*)alloc(64 * 4);
  int*   boff    = (int*)alloc(64 * 4);
  (void)ws_size;

  (void)hipMemsetAsync(deg, 0, (size_t)2 * N * 4, stream);

  const int DB = (E + 1023) / 1024;   // deg blocks (4 edges/thread)
  const int GB = (N + 31) / 32;       // gemm blocks
  const int nb = (N + 1023) / 1024;   // scan blocks (<= 64)
  wcvt_kernel<<<32, 256, 0, stream>>>(W, wfp);
  gemm_deg_kernel<<<DB + GB, 256, 0, stream>>>(feat, wfp, attn_l, attn_r,
                                               ftb, a1, a2, N, dst, deg, E, DB);
  scan_part<<<nb, 256, 0, stream>>>(deg, bsum, N);
  scan_block<<<1, 64, 0, stream>>>(bsum, boff, rowptr, nb, N);
  scan_emit<<<nb, 256, 0, stream>>>(deg, boff, rowptr, N);
  edge_scatter_kernel<<<(E + 1023) / 1024, 256, 0, stream>>>(
      src, dst, rowptr, cursor, csr_src, E);
  aggregate_kernel<<<(N + 3) / 4, 256, 0, stream>>>(ftb, a1, a2, csr_src,
                                                    rowptr, out, N);
}